// Round 1
// baseline (242.103 us; speedup 1.0000x reference)
//
#include <hip/hip_runtime.h>
#include <hip/hip_bf16.h>
#include <hip/hip_fp16.h>

#define EPS 1e-5f
#define NE_ 100000
#define B_  256

typedef _Float16 half8 __attribute__((ext_vector_type(8)));
typedef float floatx16 __attribute__((ext_vector_type(16)));

// ws layout (fp32 element offsets):
//   partials : [20][256][100]       @ 0        (512000 floats)
//   h16      : fp16 [14][256][8]    @ 512000   (57 KB)
#define WS_PART  0
#define WS_H16   512000

// =====================================================================
// Kernel 1: fused conv + fc split-K GEMM.
// Channel-aligned K-split: 20 slices x 5 channels (K=180 each) makes the
// fusion redundancy-free: block (bg, ks) computes exactly its 16x180
// slice of the conv output (each conv output computed once across the
// grid), BN1+ReLU in LDS, then the split-K GEMM vs fc_w[180x100].
// x1 never touches global memory. partials[ks][b][o].
// =====================================================================
__global__ __launch_bounds__(256) void k_convfc(
    const float* __restrict__ emb_e,
    const float* __restrict__ emb_rel,
    const float* __restrict__ bnr_g, const float* __restrict__ bnr_b,
    const float* __restrict__ bnr_m, const float* __restrict__ bnr_v,
    const float* __restrict__ bn0_g, const float* __restrict__ bn0_b,
    const float* __restrict__ bn0_m, const float* __restrict__ bn0_v,
    const float* __restrict__ bn1_g, const float* __restrict__ bn1_b,
    const float* __restrict__ bn1_m, const float* __restrict__ bn1_v,
    const float* __restrict__ fc_w,   // [3600][100]
    const int* __restrict__ e1, const int* __restrict__ rel,
    float* __restrict__ partials)     // [20][256][100]
{
    __shared__ float x0s[16][100];    // bn0-normalized entity embeddings
    __shared__ float fss[16][126];    // bn_rel-normalized filter slice (5ch x 25)
    __shared__ float x1s[16][184];    // conv output slice (5ch x 36), bn1+relu

    const int bg = blockIdx.x;        // 16 sample-groups of 16
    const int ks = blockIdx.y;        // 20 channel-chunks of 5
    const int c0 = ks * 5;
    const int b0 = bg * 16;
    const int t  = threadIdx.x;

    const float sc0 = bn0_g[0] * rsqrtf(bn0_v[0] + EPS);
    const float sh0 = bn0_b[0] - bn0_m[0] * sc0;

    // stage x0 (16 samples x 100) with bn0 applied
    for (int idx = t; idx < 16 * 100; idx += 256) {
        int s = idx / 100, j = idx - s * 100;
        x0s[s][j] = emb_e[(size_t)e1[b0 + s] * 100 + j] * sc0 + sh0;
    }
    // stage filter slice (16 samples x 125) with bn_rel applied
    for (int idx = t; idx < 16 * 125; idx += 256) {
        int s = idx / 125, j = idx - s * 125;
        int g = c0 * 25 + j;
        float sc = bnr_g[g] * rsqrtf(bnr_v[g] + EPS);
        fss[s][j] = (emb_rel[(size_t)rel[b0 + s] * 2500 + g] - bnr_m[g]) * sc + bnr_b[g];
    }
    __syncthreads();

    // conv: 16 samples x 5 channels x 36 spatial = 2880 outputs
    for (int idx = t; idx < 16 * 180; idx += 256) {
        int s = idx / 180, r = idx - s * 180;
        int cl = r / 36, p = r - cl * 36;
        int hh = p / 6, ww = p - hh * 6;
        float sum = 0.f;
        #pragma unroll
        for (int ky = 0; ky < 5; ky++) {
            #pragma unroll
            for (int kx = 0; kx < 5; kx++) {
                sum += x0s[s][(hh + ky) * 10 + ww + kx] * fss[s][cl * 25 + ky * 5 + kx];
            }
        }
        int c = c0 + cl;
        float sc = bn1_g[c] * rsqrtf(bn1_v[c] + EPS);
        float y = (sum - bn1_m[c]) * sc + bn1_b[c];
        x1s[s][r] = fmaxf(y, 0.f);
    }
    __syncthreads();

    // split-K GEMM: [16 x 180] x [180 x 100] -> partials[ks]
    const int o  = t & 127;
    const int mg = t >> 7;
    if (o >= 100) return;

    float acc[8] = {0.f, 0.f, 0.f, 0.f, 0.f, 0.f, 0.f, 0.f};
    const float* wp = fc_w + (size_t)(c0 * 36) * 100 + o;

    for (int k0 = 0; k0 < 180; k0 += 9) {
        float wv[9];
        #pragma unroll
        for (int u = 0; u < 9; u++) wv[u] = wp[(size_t)(k0 + u) * 100];
        #pragma unroll
        for (int u = 0; u < 9; u++) {
            #pragma unroll
            for (int j = 0; j < 8; j++)
                acc[j] += x1s[mg + 2 * j][k0 + u] * wv[u];
        }
    }
    #pragma unroll
    for (int j = 0; j < 8; j++)
        partials[(size_t)ks * 25600 + (size_t)(b0 + mg + 2 * j) * 100 + o] = acc[j];
}

// =====================================================================
// Kernel 2: reduce split-K + fc_b + BN2 + ReLU -> h16 in MFMA-A layout
//   h16[(k>>3)*256*8 + b*8 + (k&7)] = fp16(h[b][k]), k in [0,100); pad [100,112)=0
// =====================================================================
__global__ __launch_bounds__(256) void k_reduce(
    const float* __restrict__ partials,   // [20][256][100]
    const float* __restrict__ fc_b,
    const float* __restrict__ bn2_g, const float* __restrict__ bn2_b,
    const float* __restrict__ bn2_m, const float* __restrict__ bn2_v,
    _Float16* __restrict__ h16)           // [14][256][8]
{
    const int flat = blockIdx.x * 256 + threadIdx.x;   // b*100 + o
    const int b = flat / 100;
    const int o = flat - b * 100;
    float s = fc_b[o];
    #pragma unroll
    for (int ks = 0; ks < 20; ks++) s += partials[(size_t)ks * 25600 + flat];
    float sc = bn2_g[o] * rsqrtf(bn2_v[o] + EPS);
    float y = (s - bn2_m[o]) * sc + bn2_b[o];
    y = fmaxf(y, 0.f);
    h16[((o >> 3) * 256 + b) * 8 + (o & 7)] = (_Float16)y;
    if (o < 12) {   // zero-pad k = 100..111
        int kp = 100 + o;
        h16[((kp >> 3) * 256 + b) * 8 + (kp & 7)] = (_Float16)0.f;
    }
}

// =====================================================================
// Kernel 3: out[b][e] = sigmoid(h[b].emb_e[e] + bias[e]) via f16 MFMA.
// No LDS. Wave = 128 m x 32 n strip. Block 256 = 4 waves (4 n-strips).
// grid = (ceil(NE/128), 2 m-halves).
// A-frag: half8 from h16 chunk-major (coalesced 16B/lane).
// B-frag: built from fp32 emb row, 2 x float4 + RNE cvt; pad k>=100 -> 0.
// D layout (32x32): col = lane&31, row = (r&3) + 8*(r>>2) + 4*(lane>>5).
// =====================================================================
__global__ __launch_bounds__(256) void k_scores(
    const float* __restrict__ emb_e,
    const float* __restrict__ bias,
    const _Float16* __restrict__ h16,   // [14][256][8]
    float* __restrict__ out)            // [256][NE]
{
    const int t    = threadIdx.x;
    const int wave = t >> 6;
    const int lane = t & 63;
    const int l31  = lane & 31;
    const int hf   = lane >> 5;

    const int n0     = blockIdx.x * 128 + wave * 32;
    const int m_base = blockIdx.y * 128;

    const int e  = n0 + l31;
    const int el = (e < NE_) ? e : (NE_ - 1);
    const float* erow = emb_e + (size_t)el * 100;

    // ---- B-frags for 7 k-chunks: k = kc*16 + hf*8 + j ----
    half8 bf[7];
    #pragma unroll
    for (int kc = 0; kc < 7; kc++) {
        const int k0 = kc * 16 + hf * 8;
        half8 h;
        if (k0 + 8 <= 100) {
            const float4 f0 = *(const float4*)(erow + k0);
            const float4 f1 = *(const float4*)(erow + k0 + 4);
            h[0] = (_Float16)f0.x; h[1] = (_Float16)f0.y;
            h[2] = (_Float16)f0.z; h[3] = (_Float16)f0.w;
            h[4] = (_Float16)f1.x; h[5] = (_Float16)f1.y;
            h[6] = (_Float16)f1.z; h[7] = (_Float16)f1.w;
        } else if (k0 < 100) {   // k0 == 96: 4 valid + 4 pad
            const float4 f0 = *(const float4*)(erow + k0);
            h[0] = (_Float16)f0.x; h[1] = (_Float16)f0.y;
            h[2] = (_Float16)f0.z; h[3] = (_Float16)f0.w;
            h[4] = (_Float16)0.f; h[5] = (_Float16)0.f;
            h[6] = (_Float16)0.f; h[7] = (_Float16)0.f;
        } else {                 // k0 >= 100: all pad
            #pragma unroll
            for (int j = 0; j < 8; j++) h[j] = (_Float16)0.f;
        }
        bf[kc] = h;
    }

    const half8* hA = (const half8*)h16;   // index = chunk8*256 + m

    floatx16 acc[4];
    #pragma unroll
    for (int mt = 0; mt < 4; mt++)
        #pragma unroll
        for (int r = 0; r < 16; r++) acc[mt][r] = 0.f;

    #pragma unroll
    for (int mt = 0; mt < 4; mt++) {
        const int m = m_base + mt * 32 + l31;
        #pragma unroll
        for (int kc = 0; kc < 7; kc++) {
            const half8 a = hA[(kc * 2 + hf) * 256 + m];
            acc[mt] = __builtin_amdgcn_mfma_f32_32x32x16_f16(a, bf[kc], acc[mt], 0, 0, 0);
        }
    }

    if (e < NE_) {
        const float bb = bias[e];
        #pragma unroll
        for (int mt = 0; mt < 4; mt++) {
            #pragma unroll
            for (int r = 0; r < 16; r++) {
                const int row = m_base + mt * 32 + (r & 3) + 8 * (r >> 2) + 4 * hf;
                const float v = 1.f / (1.f + __expf(-(acc[mt][r] + bb)));
                out[(size_t)row * NE_ + e] = v;
            }
        }
    }
}

extern "C" void kernel_launch(void* const* d_in, const int* in_sizes, int n_in,
                              void* d_out, int out_size, void* d_ws, size_t ws_size,
                              hipStream_t stream) {
    const float* emb_e   = (const float*)d_in[0];
    const float* emb_rel = (const float*)d_in[1];
    const float* bnr_g   = (const float*)d_in[2];
    const float* bnr_b   = (const float*)d_in[3];
    const float* bnr_m   = (const float*)d_in[4];
    const float* bnr_v   = (const float*)d_in[5];
    const float* bn0_g   = (const float*)d_in[6];
    const float* bn0_b   = (const float*)d_in[7];
    const float* bn0_m   = (const float*)d_in[8];
    const float* bn0_v   = (const float*)d_in[9];
    const float* bn1_g   = (const float*)d_in[10];
    const float* bn1_b   = (const float*)d_in[11];
    const float* bn1_m   = (const float*)d_in[12];
    const float* bn1_v   = (const float*)d_in[13];
    const float* fc_w    = (const float*)d_in[14];
    const float* fc_b    = (const float*)d_in[15];
    const float* bn2_g   = (const float*)d_in[16];
    const float* bn2_b   = (const float*)d_in[17];
    const float* bn2_m   = (const float*)d_in[18];
    const float* bn2_v   = (const float*)d_in[19];
    const float* bias    = (const float*)d_in[20];
    const int* e1  = (const int*)d_in[21];
    const int* rel = (const int*)d_in[22];

    float* ws       = (float*)d_ws;
    float* partials = ws + WS_PART;
    _Float16* h16   = (_Float16*)(ws + WS_H16);

    k_convfc<<<dim3(16, 20), dim3(256), 0, stream>>>(
        emb_e, emb_rel,
        bnr_g, bnr_b, bnr_m, bnr_v,
        bn0_g, bn0_b, bn0_m, bn0_v,
        bn1_g, bn1_b, bn1_m, bn1_v,
        fc_w, e1, rel, partials);

    k_reduce<<<dim3(100), dim3(256), 0, stream>>>(
        partials, fc_b, bn2_g, bn2_b, bn2_m, bn2_v, h16);

    k_scores<<<dim3((NE_ + 127) / 128, 2), dim3(256), 0, stream>>>(
        emb_e, bias, h16, (float*)d_out);
}

// Round 2
// 225.493 us; speedup vs baseline: 1.0737x; 1.0737x over previous
//
#include <hip/hip_runtime.h>
#include <hip/hip_bf16.h>
#include <hip/hip_fp16.h>

#define EPS 1e-5f
#define NE_ 100000
#define B_  256

typedef _Float16 half8 __attribute__((ext_vector_type(8)));
typedef float floatx16 __attribute__((ext_vector_type(16)));

// ws layout (fp32 element offsets):
//   partials : [20][256][100]       @ 0        (512000 floats)
//   h16      : fp16 [14][256][8]    @ 512000   (57 KB)
#define WS_PART  0
#define WS_H16   512000

// =====================================================================
// Kernel 1: fused conv + fc split-K GEMM.
// Channel-aligned K-split: 20 slices x 5 channels (K=180 each) makes the
// fusion redundancy-free: block (bg, ks) computes exactly its 16x180
// slice of the conv output (each conv output computed once across the
// grid), BN1+ReLU in LDS, then the split-K GEMM vs fc_w[180x100].
// x1 never touches global memory. partials[ks][b][o].
// =====================================================================
__global__ __launch_bounds__(256) void k_convfc(
    const float* __restrict__ emb_e,
    const float* __restrict__ emb_rel,
    const float* __restrict__ bnr_g, const float* __restrict__ bnr_b,
    const float* __restrict__ bnr_m, const float* __restrict__ bnr_v,
    const float* __restrict__ bn0_g, const float* __restrict__ bn0_b,
    const float* __restrict__ bn0_m, const float* __restrict__ bn0_v,
    const float* __restrict__ bn1_g, const float* __restrict__ bn1_b,
    const float* __restrict__ bn1_m, const float* __restrict__ bn1_v,
    const float* __restrict__ fc_w,   // [3600][100]
    const int* __restrict__ e1, const int* __restrict__ rel,
    float* __restrict__ partials)     // [20][256][100]
{
    __shared__ float x0s[16][100];    // bn0-normalized entity embeddings
    __shared__ float fss[16][126];    // bn_rel-normalized filter slice (5ch x 25)
    __shared__ float x1s[16][184];    // conv output slice (5ch x 36), bn1+relu

    const int bg = blockIdx.x;        // 16 sample-groups of 16
    const int ks = blockIdx.y;        // 20 channel-chunks of 5
    const int c0 = ks * 5;
    const int b0 = bg * 16;
    const int t  = threadIdx.x;

    const float sc0 = bn0_g[0] * rsqrtf(bn0_v[0] + EPS);
    const float sh0 = bn0_b[0] - bn0_m[0] * sc0;

    // stage x0 (16 samples x 100) with bn0 applied
    for (int idx = t; idx < 16 * 100; idx += 256) {
        int s = idx / 100, j = idx - s * 100;
        x0s[s][j] = emb_e[(size_t)e1[b0 + s] * 100 + j] * sc0 + sh0;
    }
    // stage filter slice (16 samples x 125) with bn_rel applied
    for (int idx = t; idx < 16 * 125; idx += 256) {
        int s = idx / 125, j = idx - s * 125;
        int g = c0 * 25 + j;
        float sc = bnr_g[g] * rsqrtf(bnr_v[g] + EPS);
        fss[s][j] = (emb_rel[(size_t)rel[b0 + s] * 2500 + g] - bnr_m[g]) * sc + bnr_b[g];
    }
    __syncthreads();

    // conv: 16 samples x 5 channels x 36 spatial = 2880 outputs
    for (int idx = t; idx < 16 * 180; idx += 256) {
        int s = idx / 180, r = idx - s * 180;
        int cl = r / 36, p = r - cl * 36;
        int hh = p / 6, ww = p - hh * 6;
        float sum = 0.f;
        #pragma unroll
        for (int ky = 0; ky < 5; ky++) {
            #pragma unroll
            for (int kx = 0; kx < 5; kx++) {
                sum += x0s[s][(hh + ky) * 10 + ww + kx] * fss[s][cl * 25 + ky * 5 + kx];
            }
        }
        int c = c0 + cl;
        float sc = bn1_g[c] * rsqrtf(bn1_v[c] + EPS);
        float y = (sum - bn1_m[c]) * sc + bn1_b[c];
        x1s[s][r] = fmaxf(y, 0.f);
    }
    __syncthreads();

    // split-K GEMM: [16 x 180] x [180 x 100] -> partials[ks]
    const int o  = t & 127;
    const int mg = t >> 7;
    if (o >= 100) return;

    float acc[8] = {0.f, 0.f, 0.f, 0.f, 0.f, 0.f, 0.f, 0.f};
    const float* wp = fc_w + (size_t)(c0 * 36) * 100 + o;

    for (int k0 = 0; k0 < 180; k0 += 9) {
        float wv[9];
        #pragma unroll
        for (int u = 0; u < 9; u++) wv[u] = wp[(size_t)(k0 + u) * 100];
        #pragma unroll
        for (int u = 0; u < 9; u++) {
            #pragma unroll
            for (int j = 0; j < 8; j++)
                acc[j] += x1s[mg + 2 * j][k0 + u] * wv[u];
        }
    }
    #pragma unroll
    for (int j = 0; j < 8; j++)
        partials[(size_t)ks * 25600 + (size_t)(b0 + mg + 2 * j) * 100 + o] = acc[j];
}

// =====================================================================
// Kernel 2: reduce split-K + fc_b + BN2 + ReLU -> h16 in MFMA-A layout
//   h16[(k>>3)*256*8 + b*8 + (k&7)] = fp16(h[b][k]), k in [0,100); pad [100,112)=0
// =====================================================================
__global__ __launch_bounds__(256) void k_reduce(
    const float* __restrict__ partials,   // [20][256][100]
    const float* __restrict__ fc_b,
    const float* __restrict__ bn2_g, const float* __restrict__ bn2_b,
    const float* __restrict__ bn2_m, const float* __restrict__ bn2_v,
    _Float16* __restrict__ h16)           // [14][256][8]
{
    const int flat = blockIdx.x * 256 + threadIdx.x;   // b*100 + o
    const int b = flat / 100;
    const int o = flat - b * 100;
    float s = fc_b[o];
    #pragma unroll
    for (int ks = 0; ks < 20; ks++) s += partials[(size_t)ks * 25600 + flat];
    float sc = bn2_g[o] * rsqrtf(bn2_v[o] + EPS);
    float y = (s - bn2_m[o]) * sc + bn2_b[o];
    y = fmaxf(y, 0.f);
    h16[((o >> 3) * 256 + b) * 8 + (o & 7)] = (_Float16)y;
    if (o < 12) {   // zero-pad k = 100..111
        int kp = 100 + o;
        h16[((kp >> 3) * 256 + b) * 8 + (kp & 7)] = (_Float16)0.f;
    }
}

// =====================================================================
// Kernel 3: out[b][e] = sigmoid(h[b].emb_e[e] + bias[e]) via f16 MFMA.
// No LDS. Wave = 32-e strip x ALL 256 batch rows (8 m-tiles), so each
// emb_e row is fetched from HBM exactly ONCE across the grid
// (was twice with the blockIdx.y=2 split).
// Block 256 = 4 waves (4 n-strips); grid = ceil(NE/128).
// Per-mt compute->store keeps one floatx16 acc live at a time.
// A-frag: half8 from h16 chunk-major (coalesced 16B/lane, L2-resident).
// B-frag: built from fp32 emb row, 2 x float4 + RNE cvt; pad k>=100 -> 0.
// D layout (32x32): col = lane&31, row = (r&3) + 8*(r>>2) + 4*(lane>>5).
// out stores are nontemporal (write-once stream, don't flush L2).
// =====================================================================
__global__ __launch_bounds__(256) void k_scores(
    const float* __restrict__ emb_e,
    const float* __restrict__ bias,
    const _Float16* __restrict__ h16,   // [14][256][8]
    float* __restrict__ out)            // [256][NE]
{
    const int t    = threadIdx.x;
    const int wave = t >> 6;
    const int lane = t & 63;
    const int l31  = lane & 31;
    const int hf   = lane >> 5;

    const int n0 = blockIdx.x * 128 + wave * 32;

    const int e  = n0 + l31;
    const int el = (e < NE_) ? e : (NE_ - 1);
    const float* erow = emb_e + (size_t)el * 100;

    // ---- B-frags for 7 k-chunks: k = kc*16 + hf*8 + j ----
    half8 bf[7];
    #pragma unroll
    for (int kc = 0; kc < 7; kc++) {
        const int k0 = kc * 16 + hf * 8;
        half8 h;
        if (k0 + 8 <= 100) {
            const float4 f0 = *(const float4*)(erow + k0);
            const float4 f1 = *(const float4*)(erow + k0 + 4);
            h[0] = (_Float16)f0.x; h[1] = (_Float16)f0.y;
            h[2] = (_Float16)f0.z; h[3] = (_Float16)f0.w;
            h[4] = (_Float16)f1.x; h[5] = (_Float16)f1.y;
            h[6] = (_Float16)f1.z; h[7] = (_Float16)f1.w;
        } else if (k0 < 100) {   // k0 == 96: 4 valid + 4 pad
            const float4 f0 = *(const float4*)(erow + k0);
            h[0] = (_Float16)f0.x; h[1] = (_Float16)f0.y;
            h[2] = (_Float16)f0.z; h[3] = (_Float16)f0.w;
            h[4] = (_Float16)0.f; h[5] = (_Float16)0.f;
            h[6] = (_Float16)0.f; h[7] = (_Float16)0.f;
        } else {                 // k0 >= 100: all pad
            #pragma unroll
            for (int j = 0; j < 8; j++) h[j] = (_Float16)0.f;
        }
        bf[kc] = h;
    }

    const half8* hA = (const half8*)h16;   // index = chunk8*256 + m
    const float bb = (e < NE_) ? bias[e] : 0.f;

    #pragma unroll 2
    for (int mt = 0; mt < 8; mt++) {
        floatx16 acc;
        #pragma unroll
        for (int r = 0; r < 16; r++) acc[r] = 0.f;

        const int m = mt * 32 + l31;
        #pragma unroll
        for (int kc = 0; kc < 7; kc++) {
            const half8 a = hA[(kc * 2 + hf) * 256 + m];
            acc = __builtin_amdgcn_mfma_f32_32x32x16_f16(a, bf[kc], acc, 0, 0, 0);
        }

        if (e < NE_) {
            #pragma unroll
            for (int r = 0; r < 16; r++) {
                const int row = mt * 32 + (r & 3) + 8 * (r >> 2) + 4 * hf;
                const float v = 1.f / (1.f + __expf(-(acc[r] + bb)));
                __builtin_nontemporal_store(v, &out[(size_t)row * NE_ + e]);
            }
        }
    }
}

extern "C" void kernel_launch(void* const* d_in, const int* in_sizes, int n_in,
                              void* d_out, int out_size, void* d_ws, size_t ws_size,
                              hipStream_t stream) {
    const float* emb_e   = (const float*)d_in[0];
    const float* emb_rel = (const float*)d_in[1];
    const float* bnr_g   = (const float*)d_in[2];
    const float* bnr_b   = (const float*)d_in[3];
    const float* bnr_m   = (const float*)d_in[4];
    const float* bnr_v   = (const float*)d_in[5];
    const float* bn0_g   = (const float*)d_in[6];
    const float* bn0_b   = (const float*)d_in[7];
    const float* bn0_m   = (const float*)d_in[8];
    const float* bn0_v   = (const float*)d_in[9];
    const float* bn1_g   = (const float*)d_in[10];
    const float* bn1_b   = (const float*)d_in[11];
    const float* bn1_m   = (const float*)d_in[12];
    const float* bn1_v   = (const float*)d_in[13];
    const float* fc_w    = (const float*)d_in[14];
    const float* fc_b    = (const float*)d_in[15];
    const float* bn2_g   = (const float*)d_in[16];
    const float* bn2_b   = (const float*)d_in[17];
    const float* bn2_m   = (const float*)d_in[18];
    const float* bn2_v   = (const float*)d_in[19];
    const float* bias    = (const float*)d_in[20];
    const int* e1  = (const int*)d_in[21];
    const int* rel = (const int*)d_in[22];

    float* ws       = (float*)d_ws;
    float* partials = ws + WS_PART;
    _Float16* h16   = (_Float16*)(ws + WS_H16);

    k_convfc<<<dim3(16, 20), dim3(256), 0, stream>>>(
        emb_e, emb_rel,
        bnr_g, bnr_b, bnr_m, bnr_v,
        bn0_g, bn0_b, bn0_m, bn0_v,
        bn1_g, bn1_b, bn1_m, bn1_v,
        fc_w, e1, rel, partials);

    k_reduce<<<dim3(100), dim3(256), 0, stream>>>(
        partials, fc_b, bn2_g, bn2_b, bn2_m, bn2_v, h16);

    k_scores<<<dim3((NE_ + 127) / 128), dim3(256), 0, stream>>>(
        emb_e, bias, h16, (float*)d_out);
}

// Round 3
// 218.093 us; speedup vs baseline: 1.1101x; 1.0339x over previous
//
#include <hip/hip_runtime.h>
#include <hip/hip_bf16.h>
#include <hip/hip_fp16.h>

#define EPS 1e-5f
#define NE_ 100000
#define B_  256

typedef _Float16 half8 __attribute__((ext_vector_type(8)));
typedef float floatx16 __attribute__((ext_vector_type(16)));

// ws layout (fp32 element offsets):
//   partials : [20][256][100]       @ 0        (512000 floats)
//   h16      : fp16 [14][256][8]    @ 512000   (57 KB)
#define WS_PART  0
#define WS_H16   512000

// =====================================================================
// Kernel 1: fused conv + fc split-K GEMM.
// Channel-aligned K-split: 20 slices x 5 channels (K=180 each) makes the
// fusion redundancy-free. 8 samples/block (640 blocks = 2.5/CU for
// latency hiding; was 16/block = 1.25/CU). Per-(b,o) summation order
// identical to the 16-sample version -> bit-identical partials.
// =====================================================================
__global__ __launch_bounds__(256) void k_convfc(
    const float* __restrict__ emb_e,
    const float* __restrict__ emb_rel,
    const float* __restrict__ bnr_g, const float* __restrict__ bnr_b,
    const float* __restrict__ bnr_m, const float* __restrict__ bnr_v,
    const float* __restrict__ bn0_g, const float* __restrict__ bn0_b,
    const float* __restrict__ bn0_m, const float* __restrict__ bn0_v,
    const float* __restrict__ bn1_g, const float* __restrict__ bn1_b,
    const float* __restrict__ bn1_m, const float* __restrict__ bn1_v,
    const float* __restrict__ fc_w,   // [3600][100]
    const int* __restrict__ e1, const int* __restrict__ rel,
    float* __restrict__ partials)     // [20][256][100]
{
    __shared__ float x0s[8][100];     // bn0-normalized entity embeddings
    __shared__ float fss[8][126];     // bn_rel-normalized filter slice (5ch x 25)
    __shared__ float x1s[8][184];     // conv output slice (5ch x 36), bn1+relu

    const int bg = blockIdx.x;        // 32 sample-groups of 8
    const int ks = blockIdx.y;        // 20 channel-chunks of 5
    const int c0 = ks * 5;
    const int b0 = bg * 8;
    const int t  = threadIdx.x;

    const float sc0 = bn0_g[0] * rsqrtf(bn0_v[0] + EPS);
    const float sh0 = bn0_b[0] - bn0_m[0] * sc0;

    // stage x0 (8 samples x 100) with bn0 applied
    for (int idx = t; idx < 8 * 100; idx += 256) {
        int s = idx / 100, j = idx - s * 100;
        x0s[s][j] = emb_e[(size_t)e1[b0 + s] * 100 + j] * sc0 + sh0;
    }
    // stage filter slice (8 samples x 125) with bn_rel applied
    for (int idx = t; idx < 8 * 125; idx += 256) {
        int s = idx / 125, j = idx - s * 125;
        int g = c0 * 25 + j;
        float sc = bnr_g[g] * rsqrtf(bnr_v[g] + EPS);
        fss[s][j] = (emb_rel[(size_t)rel[b0 + s] * 2500 + g] - bnr_m[g]) * sc + bnr_b[g];
    }
    __syncthreads();

    // conv: 8 samples x 5 channels x 36 spatial = 1440 outputs
    for (int idx = t; idx < 8 * 180; idx += 256) {
        int s = idx / 180, r = idx - s * 180;
        int cl = r / 36, p = r - cl * 36;
        int hh = p / 6, ww = p - hh * 6;
        float sum = 0.f;
        #pragma unroll
        for (int ky = 0; ky < 5; ky++) {
            #pragma unroll
            for (int kx = 0; kx < 5; kx++) {
                sum += x0s[s][(hh + ky) * 10 + ww + kx] * fss[s][cl * 25 + ky * 5 + kx];
            }
        }
        int c = c0 + cl;
        float sc = bn1_g[c] * rsqrtf(bn1_v[c] + EPS);
        float y = (sum - bn1_m[c]) * sc + bn1_b[c];
        x1s[s][r] = fmaxf(y, 0.f);
    }
    __syncthreads();

    // split-K GEMM: [8 x 180] x [180 x 100] -> partials[ks]
    const int o  = t & 127;
    const int mg = t >> 7;
    if (o >= 100) return;

    float acc[4] = {0.f, 0.f, 0.f, 0.f};
    const float* wp = fc_w + (size_t)(c0 * 36) * 100 + o;

    for (int k0 = 0; k0 < 180; k0 += 9) {
        float wv[9];
        #pragma unroll
        for (int u = 0; u < 9; u++) wv[u] = wp[(size_t)(k0 + u) * 100];
        #pragma unroll
        for (int u = 0; u < 9; u++) {
            #pragma unroll
            for (int j = 0; j < 4; j++)
                acc[j] += x1s[mg + 2 * j][k0 + u] * wv[u];
        }
    }
    #pragma unroll
    for (int j = 0; j < 4; j++)
        partials[(size_t)ks * 25600 + (size_t)(b0 + mg + 2 * j) * 100 + o] = acc[j];
}

// =====================================================================
// Kernel 2: reduce split-K + fc_b + BN2 + ReLU -> h16 in MFMA-A layout
//   h16[(k>>3)*256*8 + b*8 + (k&7)] = fp16(h[b][k]), k in [0,100); pad [100,112)=0
// =====================================================================
__global__ __launch_bounds__(256) void k_reduce(
    const float* __restrict__ partials,   // [20][256][100]
    const float* __restrict__ fc_b,
    const float* __restrict__ bn2_g, const float* __restrict__ bn2_b,
    const float* __restrict__ bn2_m, const float* __restrict__ bn2_v,
    _Float16* __restrict__ h16)           // [14][256][8]
{
    const int flat = blockIdx.x * 256 + threadIdx.x;   // b*100 + o
    const int b = flat / 100;
    const int o = flat - b * 100;
    float s = fc_b[o];
    #pragma unroll
    for (int ks = 0; ks < 20; ks++) s += partials[(size_t)ks * 25600 + flat];
    float sc = bn2_g[o] * rsqrtf(bn2_v[o] + EPS);
    float y = (s - bn2_m[o]) * sc + bn2_b[o];
    y = fmaxf(y, 0.f);
    h16[((o >> 3) * 256 + b) * 8 + (o & 7)] = (_Float16)y;
    if (o < 12) {   // zero-pad k = 100..111
        int kp = 100 + o;
        h16[((kp >> 3) * 256 + b) * 8 + (kp & 7)] = (_Float16)0.f;
    }
}

// =====================================================================
// Kernel 3: out[b][e] = sigmoid(h[b].emb_e[e] + bias[e]) via f16 MFMA.
// Block = 128 e-cols x all 256 batch rows (8 m-tiles); grid ceil(NE/128).
// emb_e staging: the block's 128 rows are CONTIGUOUS in memory
// (51.2 KB); 256 threads stream them with coalesced float4 loads and
// write fp16 (RNE, same cvt as before) into LDS directly in MFMA-B
// fragment order: ebf[(wave*14 + kc*2 + hf)*256 + l31*8 + j].
// This replaces the per-lane 400B-stride gather (64 cache lines per
// wave-load, L1-thrashing) with a perfect stream; B-frag reads are
// contiguous-16B-per-lane ds_read_b128 (conflict-free).
// k in [100,112) zero-padded; rows >= NE zero-filled (their cols are
// never stored). Same MFMA order -> bit-identical output.
// D layout (32x32): col = lane&31, row = (r&3) + 8*(r>>2) + 4*(lane>>5).
// out stores nontemporal (write-once stream).
// =====================================================================
__global__ __launch_bounds__(256) void k_scores(
    const float* __restrict__ emb_e,
    const float* __restrict__ bias,
    const _Float16* __restrict__ h16,   // [14][256][8]
    float* __restrict__ out)            // [256][NE]
{
    __shared__ _Float16 ebf[4 * 14 * 32 * 8];   // 28 KB

    const int t    = threadIdx.x;
    const int wave = t >> 6;
    const int lane = t & 63;
    const int l31  = lane & 31;
    const int hf   = lane >> 5;

    const int n0 = blockIdx.x * 128 + wave * 32;
    const int e  = n0 + l31;

    // ---- cooperative staging: 12800 contiguous floats -> fp16 LDS ----
    {
        const size_t gbase = (size_t)blockIdx.x * 12800;
        for (int f0 = t * 4; f0 < 12800; f0 += 1024) {
            const size_t gf = gbase + f0;
            float4 v;
            if (gf + 4 <= (size_t)NE_ * 100) {       // 10,000,000 % 4 == 0: no straddle
                v = *(const float4*)(emb_e + gf);
            } else {
                v = make_float4(0.f, 0.f, 0.f, 0.f);
            }
            #pragma unroll
            for (int i = 0; i < 4; i++) {
                const int f = f0 + i;
                const int r = f / 100;
                const int k = f - r * 100;
                const int chunk = (r >> 5) * 14 + (k >> 4) * 2 + ((k >> 3) & 1);
                const float fv = (i == 0) ? v.x : (i == 1) ? v.y : (i == 2) ? v.z : v.w;
                ebf[chunk * 256 + (r & 31) * 8 + (k & 7)] = (_Float16)fv;
            }
        }
        // zero-pad k = 100..111 for all 128 rows
        for (int idx = t; idx < 128 * 12; idx += 256) {
            const int r  = idx / 12;
            const int kp = 100 + (idx - r * 12);
            const int chunk = (r >> 5) * 14 + (kp >> 4) * 2 + ((kp >> 3) & 1);
            ebf[chunk * 256 + (r & 31) * 8 + (kp & 7)] = (_Float16)0.f;
        }
    }
    __syncthreads();

    // ---- B-frags for 7 k-chunks from LDS (contiguous 16B per lane) ----
    half8 bf[7];
    {
        const half8* eb8 = (const half8*)ebf;       // index = chunk*32 + l31
        #pragma unroll
        for (int kc = 0; kc < 7; kc++)
            bf[kc] = eb8[(wave * 14 + kc * 2 + hf) * 32 + l31];
    }

    const half8* hA = (const half8*)h16;   // index = chunk8*256 + m
    const float bb = (e < NE_) ? bias[e] : 0.f;

    #pragma unroll 2
    for (int mt = 0; mt < 8; mt++) {
        floatx16 acc;
        #pragma unroll
        for (int r = 0; r < 16; r++) acc[r] = 0.f;

        const int m = mt * 32 + l31;
        #pragma unroll
        for (int kc = 0; kc < 7; kc++) {
            const half8 a = hA[(kc * 2 + hf) * 256 + m];
            acc = __builtin_amdgcn_mfma_f32_32x32x16_f16(a, bf[kc], acc, 0, 0, 0);
        }

        if (e < NE_) {
            #pragma unroll
            for (int r = 0; r < 16; r++) {
                const int row = mt * 32 + (r & 3) + 8 * (r >> 2) + 4 * hf;
                const float v = 1.f / (1.f + __expf(-(acc[r] + bb)));
                __builtin_nontemporal_store(v, &out[(size_t)row * NE_ + e]);
            }
        }
    }
}

extern "C" void kernel_launch(void* const* d_in, const int* in_sizes, int n_in,
                              void* d_out, int out_size, void* d_ws, size_t ws_size,
                              hipStream_t stream) {
    const float* emb_e   = (const float*)d_in[0];
    const float* emb_rel = (const float*)d_in[1];
    const float* bnr_g   = (const float*)d_in[2];
    const float* bnr_b   = (const float*)d_in[3];
    const float* bnr_m   = (const float*)d_in[4];
    const float* bnr_v   = (const float*)d_in[5];
    const float* bn0_g   = (const float*)d_in[6];
    const float* bn0_b   = (const float*)d_in[7];
    const float* bn0_m   = (const float*)d_in[8];
    const float* bn0_v   = (const float*)d_in[9];
    const float* bn1_g   = (const float*)d_in[10];
    const float* bn1_b   = (const float*)d_in[11];
    const float* bn1_m   = (const float*)d_in[12];
    const float* bn1_v   = (const float*)d_in[13];
    const float* fc_w    = (const float*)d_in[14];
    const float* fc_b    = (const float*)d_in[15];
    const float* bn2_g   = (const float*)d_in[16];
    const float* bn2_b   = (const float*)d_in[17];
    const float* bn2_m   = (const float*)d_in[18];
    const float* bn2_v   = (const float*)d_in[19];
    const float* bias    = (const float*)d_in[20];
    const int* e1  = (const int*)d_in[21];
    const int* rel = (const int*)d_in[22];

    float* ws       = (float*)d_ws;
    float* partials = ws + WS_PART;
    _Float16* h16   = (_Float16*)(ws + WS_H16);

    k_convfc<<<dim3(32, 20), dim3(256), 0, stream>>>(
        emb_e, emb_rel,
        bnr_g, bnr_b, bnr_m, bnr_v,
        bn0_g, bn0_b, bn0_m, bn0_v,
        bn1_g, bn1_b, bn1_m, bn1_v,
        fc_w, e1, rel, partials);

    k_reduce<<<dim3(100), dim3(256), 0, stream>>>(
        partials, fc_b, bn2_g, bn2_b, bn2_m, bn2_v, h16);

    k_scores<<<dim3((NE_ + 127) / 128), dim3(256), 0, stream>>>(
        emb_e, bias, h16, (float*)d_out);
}